// Round 6
// baseline (774.093 us; speedup 1.0000x reference)
//
#include <hip/hip_runtime.h>
#include <math.h>

#define NN 50000
#define EE 800000
#define FF 128

constexpr float LN_EPS = 1e-5f;
constexpr int NC = (NN + 255) / 256;   // 196 scan chunks

typedef float  f32x4  __attribute__((ext_vector_type(4)));
typedef short  s16x8  __attribute__((ext_vector_type(8)));

__device__ __forceinline__ float silu_f(float v) {
    return v / (1.f + __expf(-v));
}

__device__ __forceinline__ unsigned short f2bf(float f) {
    union { float f; unsigned u; } cv; cv.f = f;
    unsigned u = cv.u;
    u += 0x7fffu + ((u >> 16) & 1u);   // round-to-nearest-even
    return (unsigned short)(u >> 16);
}

__device__ __forceinline__ float bf2f(unsigned short u) {
    union { unsigned u; float f; } cv; cv.u = ((unsigned)u) << 16;
    return cv.f;
}

// -------------------- prep: x -> bf16 --------------------
__global__ __launch_bounds__(256) void convert_x_kernel(
    const float* __restrict__ x, unsigned short* __restrict__ xb)
{
    int i = (blockIdx.x * 256 + threadIdx.x) * 8;
    float4 a = *(const float4*)&x[i];
    float4 b = *(const float4*)&x[i + 4];
    s16x8 o;
    o[0] = (short)f2bf(a.x); o[1] = (short)f2bf(a.y);
    o[2] = (short)f2bf(a.z); o[3] = (short)f2bf(a.w);
    o[4] = (short)f2bf(b.x); o[5] = (short)f2bf(b.y);
    o[6] = (short)f2bf(b.z); o[7] = (short)f2bf(b.w);
    *(s16x8*)&xb[i] = o;
}

// -------------------- prep: transpose weights -> bf16 --------------------
__global__ __launch_bounds__(256) void transpose_w_kernel(
    const float* __restrict__ ew1, const float* __restrict__ ew2,
    unsigned short* __restrict__ ew1T, unsigned short* __restrict__ ew2T)
{
    int o = blockIdx.x * 256 + threadIdx.x;
    if (o < 128 * 256) {
        int n = o >> 8, k = o & 255;
        ew1T[o] = f2bf(ew1[k * FF + n]);
    } else {
        int o2 = o - 128 * 256;
        int n = o2 >> 7, k = o2 & 127;
        ew2T[o2] = f2bf(ew2[k * FF + n]);
    }
}

// -------------------- counting sort by row --------------------
__global__ __launch_bounds__(256) void hist_kernel(
    const int* __restrict__ ei, int* __restrict__ cnt)
{
    int e = blockIdx.x * 256 + threadIdx.x;
    if (e < EE) atomicAdd(&cnt[ei[e]], 1);
}

__global__ __launch_bounds__(256) void chunk_sum_kernel(
    const int* __restrict__ cnt, int* __restrict__ chunkSum)
{
    __shared__ int s[256];
    int t = threadIdx.x;
    int idx = blockIdx.x * 256 + t;
    s[t] = (idx < NN) ? cnt[idx] : 0;
    __syncthreads();
    for (int off = 128; off > 0; off >>= 1) {
        if (t < off) s[t] += s[t + off];
        __syncthreads();
    }
    if (t == 0) chunkSum[blockIdx.x] = s[0];
}

__global__ __launch_bounds__(256) void scan_chunks_kernel(
    const int* __restrict__ chunkSum, int* __restrict__ chunkOff)
{
    __shared__ int s[256];
    int t = threadIdx.x;
    int v = (t < NC) ? chunkSum[t] : 0;
    s[t] = v;
    __syncthreads();
    for (int off = 1; off < 256; off <<= 1) {
        int u = (t >= off) ? s[t - off] : 0;
        __syncthreads();
        s[t] += u;
        __syncthreads();
    }
    if (t < NC) chunkOff[t] = s[t] - v;
}

// writes BOTH offs (mutated later by scatter) and rowStart (CSR, immutable)
__global__ __launch_bounds__(256) void scan_kernel(
    const int* __restrict__ cnt, const int* __restrict__ chunkOff,
    int* __restrict__ offs, int* __restrict__ rowStart)
{
    __shared__ int s[256];
    int t = threadIdx.x;
    int idx = blockIdx.x * 256 + t;
    int v = (idx < NN) ? cnt[idx] : 0;
    s[t] = v;
    __syncthreads();
    for (int off = 1; off < 256; off <<= 1) {
        int u = (t >= off) ? s[t - off] : 0;
        __syncthreads();
        s[t] += u;
        __syncthreads();
    }
    if (idx < NN) {
        int st = chunkOff[blockIdx.x] + s[t] - v;
        offs[idx] = st;
        rowStart[idx] = st;
    }
}

__global__ __launch_bounds__(256) void scatter_idx_kernel(
    const int* __restrict__ ei, int* __restrict__ offs,
    int* __restrict__ sRow, int* __restrict__ sCol)
{
    int e = blockIdx.x * 256 + threadIdx.x;
    if (e < EE) {
        int r = ei[e], c = ei[EE + e];
        int p = atomicAdd(&offs[r], 1);
        sRow[p] = r;
        sCol[p] = c;
    }
}

// ==================== PASS A: edge MLP -> msgb, sSg (no scatter) ==========
constexpr int EPB   = 64;
constexpr int NTILE = EE / EPB;    // 12500
constexpr int XAS   = 264;         // xa stride (elems): 256 + 8 pad
constexpr int H1S   = 132;         // h1 / msgL stride (elems): 128 + 4 pad

__global__ __launch_bounds__(512, 4) void edgeA_kernel(
    const unsigned short* __restrict__ xb, const float* __restrict__ pos,
    const int* __restrict__ sRow, const int* __restrict__ sCol,
    const unsigned short* __restrict__ ew1T, const float* __restrict__ ew1,
    const float* __restrict__ eb1,
    const unsigned short* __restrict__ ew2T, const float* __restrict__ eb2,
    const float* __restrict__ cw,  const float* __restrict__ cb,
    unsigned short* __restrict__ msgb, float* __restrict__ sSg)
{
    __shared__ int   rowS[EPB];
    __shared__ int   colS[EPB];
    __shared__ float dist2S[EPB];
    __shared__ float sPart[8][EPB];
    // xa: 64 x 264 bf16 = 33792 B. Reused: h1 = elems [0, 8448), msgL = [8448, 16896).
    __shared__ __align__(16) unsigned short xa[EPB * XAS];
    unsigned short* h1   = xa;
    unsigned short* msgL = xa + EPB * H1S;   // 64*132 = 8448

    const int t   = threadIdx.x;
    const int w   = t >> 6;
    const int l   = t & 63;
    const int l15 = l & 15;
    const int q8  = l >> 4;          // 0..3
    const int n   = w * 16 + l15;    // this lane's output column

    // persistent per-lane state (in registers across all tiles)
    s16x8 B1[8], B2[4];
    #pragma unroll
    for (int ko = 0; ko < 8; ++ko)
        B1[ko] = *(const s16x8*)(ew1T + (size_t)n * 256 + ko * 32 + q8 * 8);
    #pragma unroll
    for (int ko = 0; ko < 4; ++ko)
        B2[ko] = *(const s16x8*)(ew2T + (size_t)n * 128 + ko * 32 + q8 * 8);
    const float w256 = ew1[256 * FF + n];
    const float b1   = eb1[n];
    const float b2   = eb2[n];
    const float cwc  = cw[n];
    const float cb0  = cb[0];

    for (int tile = blockIdx.x; tile < NTILE; tile += gridDim.x) {
        const int e0 = tile * EPB;

        // meta
        if (t < EPB) {
            int r = sRow[e0 + t];
            int c = sCol[e0 + t];
            rowS[t] = r;
            colS[t] = c;
            float dx = pos[r*3+0] - pos[c*3+0];
            float dy = pos[r*3+1] - pos[c*3+1];
            float dz = pos[r*3+2] - pos[c*3+2];
            dist2S[t] = dx*dx + dy*dy + dz*dz;
        }
        __syncthreads();

        // stage A tile into LDS (64 edges x 256 k, bf16)
        #pragma unroll
        for (int i = 0; i < 4; ++i) {
            int idx = i * 512 + t;          // 0..2047
            int e   = idx >> 5;             // edge
            int q   = idx & 31;             // 8-elem chunk: 0..15 row, 16..31 col
            int node = (q < 16) ? rowS[e] : colS[e];
            s16x8 v = *(const s16x8*)(xb + (size_t)node * FF + (q & 15) * 8);
            *(s16x8*)(xa + e * XAS + q * 8) = v;
        }
        __syncthreads();

        // GEMM1 (64x16 per wave, K=256), A from LDS, B from registers
        f32x4 acc[4] = {};
        #pragma unroll
        for (int mt = 0; mt < 4; ++mt) {
            const unsigned short* ar = xa + (mt * 16 + l15) * XAS + q8 * 8;
            #pragma unroll
            for (int ko = 0; ko < 8; ++ko) {
                s16x8 a = *(const s16x8*)(ar + ko * 32);
                acc[mt] = __builtin_amdgcn_mfma_f32_16x16x32_bf16(a, B1[ko], acc[mt], 0, 0, 0);
            }
        }
        __syncthreads();   // xa reads done before h1 overwrites

        // epilogue: dist2 rank-1 + bias + SiLU -> h1
        #pragma unroll
        for (int mt = 0; mt < 4; ++mt) {
            #pragma unroll
            for (int r = 0; r < 4; ++r) {
                int e = mt * 16 + q8 * 4 + r;
                float v = acc[mt][r] + dist2S[e] * w256 + b1;
                h1[e * H1S + n] = f2bf(silu_f(v));
            }
        }
        __syncthreads();

        // GEMM2 (K=128)
        f32x4 acc2[4] = {};
        #pragma unroll
        for (int mt = 0; mt < 4; ++mt) {
            const unsigned short* hr = h1 + (mt * 16 + l15) * H1S + q8 * 8;
            #pragma unroll
            for (int ko = 0; ko < 4; ++ko) {
                s16x8 a = *(const s16x8*)(hr + ko * 32);
                acc2[mt] = __builtin_amdgcn_mfma_f32_16x16x32_bf16(a, B2[ko], acc2[mt], 0, 0, 0);
            }
        }

        // coord-scale partials + msg -> msgL (msgL disjoint from h1)
        #pragma unroll
        for (int mt = 0; mt < 4; ++mt) {
            #pragma unroll
            for (int r = 0; r < 4; ++r) {
                float m = acc2[mt][r] + b2;
                float p = m * cwc;
                p += __shfl_xor(p, 1);
                p += __shfl_xor(p, 2);
                p += __shfl_xor(p, 4);
                p += __shfl_xor(p, 8);
                int e = mt * 16 + q8 * 4 + r;
                if (l15 == 0) sPart[w][e] = p;
                msgL[e * H1S + n] = f2bf(m);
            }
        }
        __syncthreads();   // sPart + msgL complete

        if (t < EPB) {
            float p = 0.f;
            #pragma unroll
            for (int ww = 0; ww < 8; ++ww) p += sPart[ww][t];
            sSg[e0 + t] = tanhf(p + cb0);
        }

        // msgL -> msgb (coalesced 16B chunks)
        #pragma unroll
        for (int i = 0; i < 2; ++i) {
            int idx = i * 512 + t;          // 0..1023
            int e   = idx >> 4;             // row
            int c   = idx & 15;             // 8-elem chunk
            *(s16x8*)&msgb[(size_t)(e0 + e) * FF + c * 8] =
                *(const s16x8*)&msgL[e * H1S + c * 8];
        }
        __syncthreads();   // protect xa/msgL before next tile
    }
}

// ==================== PASS B: CSR gather + node MLP + LN + pos ============
constexpr int NPB  = 16;
constexpr int HSTR = 132;

__global__ __launch_bounds__(128) void nodeB_kernel(
    const float* __restrict__ x, const float* __restrict__ pos,
    const unsigned short* __restrict__ msgb, const float* __restrict__ sSg,
    const int* __restrict__ sCol, const int* __restrict__ rowStart,
    const float* __restrict__ nw1, const float* __restrict__ nb1,
    const float* __restrict__ nw2, const float* __restrict__ nb2,
    const float* __restrict__ gamma, const float* __restrict__ beta,
    float* __restrict__ xout, float* __restrict__ posout)
{
    __shared__ __align__(16) float a[NPB * HSTR];
    __shared__ __align__(16) float h1[NPB * HSTR];
    __shared__ float red[2][NPB][2];

    const int t  = threadIdx.x;
    const int n0 = blockIdx.x * NPB;

    // CSR gather: agg[e][t] = sum of msgb rows (contiguous, coalesced)
    for (int e = 0; e < NPB; ++e) {
        int nn = n0 + e;
        int p0 = rowStart[nn];
        int p1 = (nn == NN - 1) ? EE : rowStart[nn + 1];
        float s0 = 0.f, s1 = 0.f, s2 = 0.f, s3 = 0.f;
        int p = p0;
        for (; p + 4 <= p1; p += 4) {
            s0 += bf2f(msgb[(size_t)(p    ) * FF + t]);
            s1 += bf2f(msgb[(size_t)(p + 1) * FF + t]);
            s2 += bf2f(msgb[(size_t)(p + 2) * FF + t]);
            s3 += bf2f(msgb[(size_t)(p + 3) * FF + t]);
        }
        for (; p < p1; ++p) s0 += bf2f(msgb[(size_t)p * FF + t]);
        a[e * HSTR + t] = (s0 + s1) + (s2 + s3);
    }

    // pos update (overlaps with gather of other waves/blocks)
    if (t < NPB * 3) {
        int e = t / 3, d = t % 3;
        int nn = n0 + e;
        int p0 = rowStart[nn];
        int p1 = (nn == NN - 1) ? EE : rowStart[nn + 1];
        float pn = pos[nn * 3 + d];
        float sum = 0.f;
        for (int p = p0; p < p1; ++p) {
            int c = sCol[p];
            sum += sSg[p] * (pn - pos[c * 3 + d]);
        }
        posout[nn * 3 + d] = pn + sum;
    }
    __syncthreads();

    // GEMM1: h1 = silu(a @ nw1 + nb1)
    float acc[NPB];
    {
        float b = nb1[t];
        #pragma unroll
        for (int e = 0; e < NPB; ++e) acc[e] = b;
    }
    for (int k = 0; k < 128; k += 4) {
        float w0 = nw1[(k+0)*FF + t];
        float w1 = nw1[(k+1)*FF + t];
        float w2 = nw1[(k+2)*FF + t];
        float w3 = nw1[(k+3)*FF + t];
        #pragma unroll
        for (int e = 0; e < NPB; ++e) {
            float4 f = *(const float4*)&a[e*HSTR + k];
            acc[e] = fmaf(f.x, w0, acc[e]);
            acc[e] = fmaf(f.y, w1, acc[e]);
            acc[e] = fmaf(f.z, w2, acc[e]);
            acc[e] = fmaf(f.w, w3, acc[e]);
        }
    }
    #pragma unroll
    for (int e = 0; e < NPB; ++e) h1[e*HSTR + t] = silu_f(acc[e]);
    __syncthreads();

    // GEMM2: upd = h1 @ nw2 + nb2
    float upd[NPB];
    {
        float b = nb2[t];
        #pragma unroll
        for (int e = 0; e < NPB; ++e) upd[e] = b;
    }
    for (int k = 0; k < 128; k += 4) {
        float w0 = nw2[(k+0)*FF + t];
        float w1 = nw2[(k+1)*FF + t];
        float w2 = nw2[(k+2)*FF + t];
        float w3 = nw2[(k+3)*FF + t];
        #pragma unroll
        for (int e = 0; e < NPB; ++e) {
            float4 f = *(const float4*)&h1[e*HSTR + k];
            upd[e] = fmaf(f.x, w0, upd[e]);
            upd[e] = fmaf(f.y, w1, upd[e]);
            upd[e] = fmaf(f.z, w2, upd[e]);
            upd[e] = fmaf(f.w, w3, upd[e]);
        }
    }

    // residual + LayerNorm
    #pragma unroll
    for (int e = 0; e < NPB; ++e) {
        float pre = x[((size_t)(n0 + e)) * FF + t] + upd[e];
        float s  = pre;
        float s2 = pre * pre;
        #pragma unroll
        for (int off = 32; off >= 1; off >>= 1) {
            s  += __shfl_down(s,  off);
            s2 += __shfl_down(s2, off);
        }
        if ((t & 63) == 0) { red[t >> 6][e][0] = s; red[t >> 6][e][1] = s2; }
        upd[e] = pre;
    }
    __syncthreads();

    {
        float g = gamma[t], b = beta[t];
        #pragma unroll
        for (int e = 0; e < NPB; ++e) {
            float mean = (red[0][e][0] + red[1][e][0]) * (1.f / FF);
            float m2   = (red[0][e][1] + red[1][e][1]) * (1.f / FF);
            float var  = m2 - mean * mean;
            float xo   = g * (upd[e] - mean) * rsqrtf(var + LN_EPS) + b;
            xout[((size_t)(n0 + e)) * FF + t] = xo;
        }
    }
}

// ==================== FALLBACK (R5 path, used if ws_size too small) =======
__global__ __launch_bounds__(512, 4) void edge_fused_kernel(
    const unsigned short* __restrict__ xb, const float* __restrict__ pos,
    const int* __restrict__ sRow, const int* __restrict__ sCol,
    const unsigned short* __restrict__ ew1T, const float* __restrict__ ew1,
    const float* __restrict__ eb1,
    const unsigned short* __restrict__ ew2T, const float* __restrict__ eb2,
    const float* __restrict__ cw,  const float* __restrict__ cb,
    float* __restrict__ agg, float* __restrict__ delta)
{
    __shared__ int   rowS[EPB];
    __shared__ int   colS[EPB];
    __shared__ int   rowD[EPB];
    __shared__ int   segStart[EPB];
    __shared__ int   segEnd[EPB];
    __shared__ int   nsegS;
    __shared__ float diffS[EPB][3];
    __shared__ float dist2S[EPB];
    __shared__ float sPart[8][EPB];
    __shared__ float sS[EPB];
    __shared__ __align__(16) unsigned short xa[EPB * XAS];
    unsigned short* h1   = xa;
    unsigned short* msgL = xa + EPB * H1S;

    const int t   = threadIdx.x;
    const int w   = t >> 6;
    const int l   = t & 63;
    const int l15 = l & 15;
    const int q8  = l >> 4;
    const int n   = w * 16 + l15;

    s16x8 B1[8], B2[4];
    #pragma unroll
    for (int ko = 0; ko < 8; ++ko)
        B1[ko] = *(const s16x8*)(ew1T + (size_t)n * 256 + ko * 32 + q8 * 8);
    #pragma unroll
    for (int ko = 0; ko < 4; ++ko)
        B2[ko] = *(const s16x8*)(ew2T + (size_t)n * 128 + ko * 32 + q8 * 8);
    const float w256 = ew1[256 * FF + n];
    const float b1   = eb1[n];
    const float b2   = eb2[n];
    const float cwc  = cw[n];
    const float cb0  = cb[0];

    for (int tile = blockIdx.x; tile < NTILE; tile += gridDim.x) {
        const int e0 = tile * EPB;

        if (t < EPB) {
            int r = sRow[e0 + t];
            int c = sCol[e0 + t];
            rowS[t] = r;
            colS[t] = c;
            float dx = pos[r*3+0] - pos[c*3+0];
            float dy = pos[r*3+1] - pos[c*3+1];
            float dz = pos[r*3+2] - pos[c*3+2];
            diffS[t][0] = dx; diffS[t][1] = dy; diffS[t][2] = dz;
            dist2S[t] = dx*dx + dy*dy + dz*dz;

            int rPrev = __shfl_up(r, 1);
            int flag  = (l == 0) || (r != rPrev);
            unsigned long long mask = __ballot(flag);
            int seg = (int)__popcll(mask & ((2ull << l) - 1ull)) - 1;
            if (flag) { rowD[seg] = r; segStart[seg] = l; }
            if (flag && l > 0) segEnd[seg - 1] = l;
            if (l == 63) { segEnd[seg] = EPB; nsegS = (int)__popcll(mask); }
        }
        __syncthreads();

        #pragma unroll
        for (int i = 0; i < 4; ++i) {
            int idx = i * 512 + t;
            int e   = idx >> 5;
            int q   = idx & 31;
            int node = (q < 16) ? rowS[e] : colS[e];
            s16x8 v = *(const s16x8*)(xb + (size_t)node * FF + (q & 15) * 8);
            *(s16x8*)(xa + e * XAS + q * 8) = v;
        }
        __syncthreads();

        f32x4 acc[4] = {};
        #pragma unroll
        for (int mt = 0; mt < 4; ++mt) {
            const unsigned short* ar = xa + (mt * 16 + l15) * XAS + q8 * 8;
            #pragma unroll
            for (int ko = 0; ko < 8; ++ko) {
                s16x8 aa = *(const s16x8*)(ar + ko * 32);
                acc[mt] = __builtin_amdgcn_mfma_f32_16x16x32_bf16(aa, B1[ko], acc[mt], 0, 0, 0);
            }
        }
        __syncthreads();

        #pragma unroll
        for (int mt = 0; mt < 4; ++mt) {
            #pragma unroll
            for (int r = 0; r < 4; ++r) {
                int e = mt * 16 + q8 * 4 + r;
                float v = acc[mt][r] + dist2S[e] * w256 + b1;
                h1[e * H1S + n] = f2bf(silu_f(v));
            }
        }
        __syncthreads();

        f32x4 acc2[4] = {};
        #pragma unroll
        for (int mt = 0; mt < 4; ++mt) {
            const unsigned short* hr = h1 + (mt * 16 + l15) * H1S + q8 * 8;
            #pragma unroll
            for (int ko = 0; ko < 4; ++ko) {
                s16x8 aa = *(const s16x8*)(hr + ko * 32);
                acc2[mt] = __builtin_amdgcn_mfma_f32_16x16x32_bf16(aa, B2[ko], acc2[mt], 0, 0, 0);
            }
        }

        #pragma unroll
        for (int mt = 0; mt < 4; ++mt) {
            #pragma unroll
            for (int r = 0; r < 4; ++r) {
                float m = acc2[mt][r] + b2;
                float p = m * cwc;
                p += __shfl_xor(p, 1);
                p += __shfl_xor(p, 2);
                p += __shfl_xor(p, 4);
                p += __shfl_xor(p, 8);
                int e = mt * 16 + q8 * 4 + r;
                if (l15 == 0) sPart[w][e] = p;
                msgL[e * H1S + n] = f2bf(m);
            }
        }
        __syncthreads();

        if (t < EPB) {
            float p = 0.f;
            #pragma unroll
            for (int ww = 0; ww < 8; ++ww) p += sPart[ww][t];
            sS[t] = tanhf(p + cb0);
        }
        __syncthreads();

        const int nseg = nsegS;
        {
            int f = t & 127;
            for (int s = t >> 7; s < nseg; s += 4) {
                float sum = 0.f;
                int eEnd = segEnd[s];
                for (int e = segStart[s]; e < eEnd; ++e)
                    sum += bf2f(msgL[e * H1S + f]);
                atomicAdd(&agg[(size_t)rowD[s] * FF + f], sum);
            }
        }
        if (t < nseg * 3) {
            int s = t / 3, d = t % 3;
            float sum = 0.f;
            int eEnd = segEnd[s];
            for (int e = segStart[s]; e < eEnd; ++e)
                sum += sS[e] * diffS[e][d];
            atomicAdd(&delta[(size_t)rowD[s] * 3 + d], sum);
        }
        __syncthreads();
    }
}

__global__ __launch_bounds__(128) void node_fb_kernel(
    const float* __restrict__ x, const float* __restrict__ pos,
    const float* __restrict__ agg, const float* __restrict__ delta,
    const float* __restrict__ nw1, const float* __restrict__ nb1,
    const float* __restrict__ nw2, const float* __restrict__ nb2,
    const float* __restrict__ gamma, const float* __restrict__ beta,
    float* __restrict__ xout, float* __restrict__ posout)
{
    __shared__ __align__(16) float a[NPB * HSTR];
    __shared__ __align__(16) float h1[NPB * HSTR];
    __shared__ float red[2][NPB][2];

    const int t  = threadIdx.x;
    const int n0 = blockIdx.x * NPB;

    #pragma unroll
    for (int i = 0; i < 4; ++i) {
        int idx = i * 128 + t;
        int e   = idx >> 5;
        int q   = idx & 31;
        *(float4*)&a[e*HSTR + q*4] =
            *(const float4*)&agg[((size_t)(n0 + e)) * FF + q*4];
    }
    __syncthreads();

    float acc[NPB];
    {
        float b = nb1[t];
        #pragma unroll
        for (int e = 0; e < NPB; ++e) acc[e] = b;
    }
    for (int k = 0; k < 128; k += 4) {
        float w0 = nw1[(k+0)*FF + t];
        float w1 = nw1[(k+1)*FF + t];
        float w2 = nw1[(k+2)*FF + t];
        float w3 = nw1[(k+3)*FF + t];
        #pragma unroll
        for (int e = 0; e < NPB; ++e) {
            float4 f = *(const float4*)&a[e*HSTR + k];
            acc[e] = fmaf(f.x, w0, acc[e]);
            acc[e] = fmaf(f.y, w1, acc[e]);
            acc[e] = fmaf(f.z, w2, acc[e]);
            acc[e] = fmaf(f.w, w3, acc[e]);
        }
    }
    #pragma unroll
    for (int e = 0; e < NPB; ++e) h1[e*HSTR + t] = silu_f(acc[e]);
    __syncthreads();

    float upd[NPB];
    {
        float b = nb2[t];
        #pragma unroll
        for (int e = 0; e < NPB; ++e) upd[e] = b;
    }
    for (int k = 0; k < 128; k += 4) {
        float w0 = nw2[(k+0)*FF + t];
        float w1 = nw2[(k+1)*FF + t];
        float w2 = nw2[(k+2)*FF + t];
        float w3 = nw2[(k+3)*FF + t];
        #pragma unroll
        for (int e = 0; e < NPB; ++e) {
            float4 f = *(const float4*)&h1[e*HSTR + k];
            upd[e] = fmaf(f.x, w0, upd[e]);
            upd[e] = fmaf(f.y, w1, upd[e]);
            upd[e] = fmaf(f.z, w2, upd[e]);
            upd[e] = fmaf(f.w, w3, upd[e]);
        }
    }

    #pragma unroll
    for (int e = 0; e < NPB; ++e) {
        float pre = x[((size_t)(n0 + e)) * FF + t] + upd[e];
        float s  = pre;
        float s2 = pre * pre;
        #pragma unroll
        for (int off = 32; off >= 1; off >>= 1) {
            s  += __shfl_down(s,  off);
            s2 += __shfl_down(s2, off);
        }
        if ((t & 63) == 0) { red[t >> 6][e][0] = s; red[t >> 6][e][1] = s2; }
        upd[e] = pre;
    }
    __syncthreads();

    {
        float g = gamma[t], b = beta[t];
        #pragma unroll
        for (int e = 0; e < NPB; ++e) {
            float mean = (red[0][e][0] + red[1][e][0]) * (1.f / FF);
            float m2   = (red[0][e][1] + red[1][e][1]) * (1.f / FF);
            float var  = m2 - mean * mean;
            float xo   = g * (upd[e] - mean) * rsqrtf(var + LN_EPS) + b;
            xout[((size_t)(n0 + e)) * FF + t] = xo;
        }
    }

    if (t < NPB * 3) {
        int e = t / 3, d = t % 3;
        size_t nn = (size_t)(n0 + e);
        posout[nn*3 + d] = pos[nn*3 + d] + delta[nn*3 + d];
    }
}

// -------------------- launcher --------------------
extern "C" void kernel_launch(void* const* d_in, const int* in_sizes, int n_in,
                              void* d_out, int out_size, void* d_ws, size_t ws_size,
                              hipStream_t stream) {
    const float* x    = (const float*)d_in[0];
    const float* pos  = (const float*)d_in[1];
    const int*   ei   = (const int*)  d_in[2];
    const float* ew1  = (const float*)d_in[3];
    const float* eb1  = (const float*)d_in[4];
    const float* ew2  = (const float*)d_in[5];
    const float* eb2  = (const float*)d_in[6];
    const float* nw1  = (const float*)d_in[7];
    const float* nb1  = (const float*)d_in[8];
    const float* nw2  = (const float*)d_in[9];
    const float* nb2  = (const float*)d_in[10];
    const float* cw   = (const float*)d_in[11];
    const float* cb   = (const float*)d_in[12];
    const float* gam  = (const float*)d_in[13];
    const float* bet  = (const float*)d_in[14];

    float* out    = (float*)d_out;
    float* xout   = out;
    float* posout = out + (size_t)NN * FF;

    auto align256 = [](size_t v) { return (v + 255) & ~(size_t)255; };
    char* ws = (char*)d_ws;

    // common small blocks
    size_t CNT_B   = align256((size_t)NN * 4);
    size_t OFFS_B  = align256((size_t)NN * 4);
    size_t RST_B   = align256((size_t)NN * 4);
    size_t CHNK_B  = align256((size_t)NC * 4 * 2);
    size_t SROW_B  = align256((size_t)EE * 4);
    size_t XB_B    = align256((size_t)NN * FF * 2);
    size_t EW1T_B  = align256((size_t)128 * 256 * 2);
    size_t EW2T_B  = align256((size_t)128 * 128 * 2);
    size_t MSGB_B  = align256((size_t)EE * FF * 2);   // 204.8 MB
    size_t SSG_B   = align256((size_t)EE * 4);

    size_t commonB = CNT_B + OFFS_B + RST_B + CHNK_B + 2 * SROW_B + XB_B + EW1T_B + EW2T_B;
    size_t needA   = commonB + MSGB_B + SSG_B;

    size_t o = 0;
    int* cnt       = (int*)(ws + o);  o += CNT_B;    // zeroed
    int* offs      = (int*)(ws + o);  o += OFFS_B;
    int* rowStart  = (int*)(ws + o);  o += RST_B;
    int* chunkSum  = (int*)(ws + o);
    int* chunkOff  = chunkSum + NC;   o += CHNK_B;
    int* sRow      = (int*)(ws + o);  o += SROW_B;
    int* sCol      = (int*)(ws + o);  o += SROW_B;
    unsigned short* xb   = (unsigned short*)(ws + o);  o += XB_B;
    unsigned short* ew1T = (unsigned short*)(ws + o);  o += EW1T_B;
    unsigned short* ew2T = (unsigned short*)(ws + o);  o += EW2T_B;

    hipMemsetAsync(cnt, 0, CNT_B, stream);

    convert_x_kernel<<<(NN * FF / 8) / 256, 256, 0, stream>>>(x, xb);
    transpose_w_kernel<<<(128 * 256 + 128 * 128) / 256, 256, 0, stream>>>(ew1, ew2, ew1T, ew2T);

    hist_kernel<<<(EE + 255) / 256, 256, 0, stream>>>(ei, cnt);
    chunk_sum_kernel<<<NC, 256, 0, stream>>>(cnt, chunkSum);
    scan_chunks_kernel<<<1, 256, 0, stream>>>(chunkSum, chunkOff);
    scan_kernel<<<NC, 256, 0, stream>>>(cnt, chunkOff, offs, rowStart);
    scatter_idx_kernel<<<(EE + 255) / 256, 256, 0, stream>>>(ei, offs, sRow, sCol);

    if (ws_size >= needA) {
        // two-pass path
        unsigned short* msgb = (unsigned short*)(ws + o);
        float*          sSg  = (float*)(ws + o + MSGB_B);

        edgeA_kernel<<<2048, 512, 0, stream>>>(
            xb, pos, sRow, sCol, ew1T, ew1, eb1, ew2T, eb2, cw, cb, msgb, sSg);

        nodeB_kernel<<<NN / NPB, 128, 0, stream>>>(
            x, pos, msgb, sSg, sCol, rowStart,
            nw1, nb1, nw2, nb2, gam, bet, xout, posout);
    } else {
        // fallback: fused scatter path (R5)
        float* agg   = (float*)(ws + o);
        float* delta = agg + (size_t)NN * FF;

        hipMemsetAsync(agg, 0, ((size_t)NN * FF + (size_t)NN * 3) * sizeof(float), stream);

        edge_fused_kernel<<<1024, 512, 0, stream>>>(
            xb, pos, sRow, sCol, ew1T, ew1, eb1, ew2T, eb2, cw, cb, agg, delta);

        node_fb_kernel<<<NN / NPB, 128, 0, stream>>>(
            x, pos, agg, delta, nw1, nb1, nw2, nb2, gam, bet, xout, posout);
    }
}

// Round 7
// 527.632 us; speedup vs baseline: 1.4671x; 1.4671x over previous
//
#include <hip/hip_runtime.h>
#include <math.h>

#define NN 50000
#define EE 800000
#define FF 128

constexpr float LN_EPS = 1e-5f;
constexpr int NC = (NN + 255) / 256;   // 196 scan chunks

typedef float  f32x4  __attribute__((ext_vector_type(4)));
typedef short  s16x8  __attribute__((ext_vector_type(8)));

__device__ __forceinline__ float silu_f(float v) {
    return v / (1.f + __expf(-v));
}

__device__ __forceinline__ unsigned short f2bf(float f) {
    union { float f; unsigned u; } cv; cv.f = f;
    unsigned u = cv.u;
    u += 0x7fffu + ((u >> 16) & 1u);   // round-to-nearest-even
    return (unsigned short)(u >> 16);
}

__device__ __forceinline__ float bf2f(unsigned short u) {
    union { unsigned u; float f; } cv; cv.u = ((unsigned)u) << 16;
    return cv.f;
}

// -------------------- prep: x -> bf16 --------------------
__global__ __launch_bounds__(256) void convert_x_kernel(
    const float* __restrict__ x, unsigned short* __restrict__ xb)
{
    int i = (blockIdx.x * 256 + threadIdx.x) * 8;
    float4 a = *(const float4*)&x[i];
    float4 b = *(const float4*)&x[i + 4];
    s16x8 o;
    o[0] = (short)f2bf(a.x); o[1] = (short)f2bf(a.y);
    o[2] = (short)f2bf(a.z); o[3] = (short)f2bf(a.w);
    o[4] = (short)f2bf(b.x); o[5] = (short)f2bf(b.y);
    o[6] = (short)f2bf(b.z); o[7] = (short)f2bf(b.w);
    *(s16x8*)&xb[i] = o;
}

// -------------------- prep: transpose all weights -> bf16 --------------------
// ew1T[n][k] (128x256), ew2T/nw1T/nw2T[n][k] (128x128)
__global__ __launch_bounds__(256) void transpose_w_kernel(
    const float* __restrict__ ew1, const float* __restrict__ ew2,
    const float* __restrict__ nw1, const float* __restrict__ nw2,
    unsigned short* __restrict__ ew1T, unsigned short* __restrict__ ew2T,
    unsigned short* __restrict__ nw1T, unsigned short* __restrict__ nw2T)
{
    int o = blockIdx.x * 256 + threadIdx.x;
    if (o < 32768) {
        int n = o >> 8, k = o & 255;
        ew1T[o] = f2bf(ew1[k * FF + n]);
    } else if (o < 49152) {
        int o2 = o - 32768; int n = o2 >> 7, k = o2 & 127;
        ew2T[o2] = f2bf(ew2[k * FF + n]);
    } else if (o < 65536) {
        int o2 = o - 49152; int n = o2 >> 7, k = o2 & 127;
        nw1T[o2] = f2bf(nw1[k * FF + n]);
    } else {
        int o2 = o - 65536; int n = o2 >> 7, k = o2 & 127;
        nw2T[o2] = f2bf(nw2[k * FF + n]);
    }
}

// -------------------- counting sort by row --------------------
__global__ __launch_bounds__(256) void hist_kernel(
    const int* __restrict__ ei, int* __restrict__ cnt)
{
    int e = blockIdx.x * 256 + threadIdx.x;
    if (e < EE) atomicAdd(&cnt[ei[e]], 1);
}

__global__ __launch_bounds__(256) void chunk_sum_kernel(
    const int* __restrict__ cnt, int* __restrict__ chunkSum)
{
    __shared__ int s[256];
    int t = threadIdx.x;
    int idx = blockIdx.x * 256 + t;
    s[t] = (idx < NN) ? cnt[idx] : 0;
    __syncthreads();
    for (int off = 128; off > 0; off >>= 1) {
        if (t < off) s[t] += s[t + off];
        __syncthreads();
    }
    if (t == 0) chunkSum[blockIdx.x] = s[0];
}

__global__ __launch_bounds__(256) void scan_chunks_kernel(
    const int* __restrict__ chunkSum, int* __restrict__ chunkOff)
{
    __shared__ int s[256];
    int t = threadIdx.x;
    int v = (t < NC) ? chunkSum[t] : 0;
    s[t] = v;
    __syncthreads();
    for (int off = 1; off < 256; off <<= 1) {
        int u = (t >= off) ? s[t - off] : 0;
        __syncthreads();
        s[t] += u;
        __syncthreads();
    }
    if (t < NC) chunkOff[t] = s[t] - v;
}

__global__ __launch_bounds__(256) void scan_kernel(
    const int* __restrict__ cnt, const int* __restrict__ chunkOff,
    int* __restrict__ offs, int* __restrict__ rowStart)
{
    __shared__ int s[256];
    int t = threadIdx.x;
    int idx = blockIdx.x * 256 + t;
    int v = (idx < NN) ? cnt[idx] : 0;
    s[t] = v;
    __syncthreads();
    for (int off = 1; off < 256; off <<= 1) {
        int u = (t >= off) ? s[t - off] : 0;
        __syncthreads();
        s[t] += u;
        __syncthreads();
    }
    if (idx < NN) {
        int st = chunkOff[blockIdx.x] + s[t] - v;
        offs[idx] = st;
        rowStart[idx] = st;
    }
}

__global__ __launch_bounds__(256) void scatter_idx_kernel(
    const int* __restrict__ ei, int* __restrict__ offs,
    int* __restrict__ sRow, int* __restrict__ sCol)
{
    int e = blockIdx.x * 256 + threadIdx.x;
    if (e < EE) {
        int r = ei[e], c = ei[EE + e];
        int p = atomicAdd(&offs[r], 1);
        sRow[p] = r;
        sCol[p] = c;
    }
}

// ==================== PASS A: edge MLP -> msgb, sSg (pipelined) ===========
constexpr int EPB   = 64;
constexpr int NTILE = EE / EPB;    // 12500
constexpr int XAS   = 264;         // xa stride: 528 B row = 33 quads (odd) -> uniform banks
constexpr int H1S   = 136;         // h1/msgL stride: 272 B row = 17 quads (odd)

__global__ __launch_bounds__(512, 4) void edgeA_kernel(
    const unsigned short* __restrict__ xb, const float* __restrict__ pos,
    const int* __restrict__ sRow, const int* __restrict__ sCol,
    const unsigned short* __restrict__ ew1T, const float* __restrict__ ew1,
    const float* __restrict__ eb1,
    const unsigned short* __restrict__ ew2T, const float* __restrict__ eb2,
    const float* __restrict__ cw,  const float* __restrict__ cb,
    unsigned short* __restrict__ msgb, float* __restrict__ sSg)
{
    __shared__ float dist2S[EPB];
    __shared__ float sPart[8][EPB];
    __shared__ __align__(16) unsigned short xa  [EPB * XAS];   // 33792 B
    __shared__ __align__(16) unsigned short h1  [EPB * H1S];   // 17408 B
    __shared__ __align__(16) unsigned short msgL[EPB * H1S];   // 17408 B

    const int t   = threadIdx.x;
    const int w   = t >> 6;
    const int l   = t & 63;
    const int l15 = l & 15;
    const int q8  = l >> 4;          // 0..3
    const int n   = w * 16 + l15;    // this lane's output column

    // persistent per-lane weights (registers for whole kernel)
    s16x8 B1[8], B2[4];
    #pragma unroll
    for (int ko = 0; ko < 8; ++ko)
        B1[ko] = *(const s16x8*)(ew1T + (size_t)n * 256 + ko * 32 + q8 * 8);
    #pragma unroll
    for (int ko = 0; ko < 4; ++ko)
        B2[ko] = *(const s16x8*)(ew2T + (size_t)n * 128 + ko * 32 + q8 * 8);
    const float w256 = ew1[256 * FF + n];
    const float b1   = eb1[n];
    const float b2   = eb2[n];
    const float cwc  = cw[n];
    const float cb0  = cb[0];

    // per-thread staging geometry: thread covers edges eB+16i (i<4), chunk q
    const int q   = t & 31;                  // 0..15 row-half, 16..31 col-half
    const int eB  = t >> 5;                  // 0..15
    const int ksel = (q & 15) * 8;
    const int* idxBase = (q < 16) ? sRow : sCol;

    // prologue: prefetch tile 0
    int   nidx[4];
    s16x8 ag[4];
    {
        int e0 = blockIdx.x * EPB;
        #pragma unroll
        for (int i = 0; i < 4; ++i) nidx[i] = idxBase[e0 + eB + 16 * i];
        #pragma unroll
        for (int i = 0; i < 4; ++i) ag[i] = *(const s16x8*)(xb + (size_t)nidx[i] * FF + ksel);
    }

    for (int tile = blockIdx.x; tile < NTILE; tile += gridDim.x) {
        const int e0 = tile * EPB;

        // commit staged regs -> xa; wave 0 computes dist2
        #pragma unroll
        for (int i = 0; i < 4; ++i)
            *(s16x8*)(xa + (eB + 16 * i) * XAS + q * 8) = ag[i];
        if (t < EPB) {
            int r = sRow[e0 + t];
            int c = sCol[e0 + t];
            float dx = pos[r*3+0] - pos[c*3+0];
            float dy = pos[r*3+1] - pos[c*3+1];
            float dz = pos[r*3+2] - pos[c*3+2];
            dist2S[t] = dx*dx + dy*dy + dz*dz;
        }
        __syncthreads();   // (A) xa + dist2S visible

        // prefetch NEXT tile into registers (latency hides behind GEMMs)
        {
            int tn  = tile + gridDim.x;
            int e0n = (tn < NTILE) ? tn * EPB : 0;
            #pragma unroll
            for (int i = 0; i < 4; ++i) nidx[i] = idxBase[e0n + eB + 16 * i];
            #pragma unroll
            for (int i = 0; i < 4; ++i) ag[i] = *(const s16x8*)(xb + (size_t)nidx[i] * FF + ksel);
        }

        // GEMM1 (K=256): A from LDS, B from registers
        f32x4 acc[4] = {};
        #pragma unroll
        for (int mt = 0; mt < 4; ++mt) {
            const unsigned short* ar = xa + (mt * 16 + l15) * XAS + q8 * 8;
            #pragma unroll
            for (int ko = 0; ko < 8; ++ko) {
                s16x8 a = *(const s16x8*)(ar + ko * 32);
                acc[mt] = __builtin_amdgcn_mfma_f32_16x16x32_bf16(a, B1[ko], acc[mt], 0, 0, 0);
            }
        }

        // epilogue: dist2 rank-1 + bias + SiLU -> h1 (separate region)
        #pragma unroll
        for (int mt = 0; mt < 4; ++mt) {
            #pragma unroll
            for (int r = 0; r < 4; ++r) {
                int e = mt * 16 + q8 * 4 + r;
                float v = acc[mt][r] + dist2S[e] * w256 + b1;
                h1[e * H1S + n] = f2bf(silu_f(v));
            }
        }
        __syncthreads();   // (B) h1 visible; xa reads done

        // GEMM2 (K=128)
        f32x4 acc2[4] = {};
        #pragma unroll
        for (int mt = 0; mt < 4; ++mt) {
            const unsigned short* hr = h1 + (mt * 16 + l15) * H1S + q8 * 8;
            #pragma unroll
            for (int ko = 0; ko < 4; ++ko) {
                s16x8 a = *(const s16x8*)(hr + ko * 32);
                acc2[mt] = __builtin_amdgcn_mfma_f32_16x16x32_bf16(a, B2[ko], acc2[mt], 0, 0, 0);
            }
        }

        // coord-scale partials + msg -> msgL
        #pragma unroll
        for (int mt = 0; mt < 4; ++mt) {
            #pragma unroll
            for (int r = 0; r < 4; ++r) {
                float m = acc2[mt][r] + b2;
                float p = m * cwc;
                p += __shfl_xor(p, 1);
                p += __shfl_xor(p, 2);
                p += __shfl_xor(p, 4);
                p += __shfl_xor(p, 8);
                int e = mt * 16 + q8 * 4 + r;
                if (l15 == 0) sPart[w][e] = p;
                msgL[e * H1S + n] = f2bf(m);
            }
        }
        __syncthreads();   // (C) sPart + msgL visible

        if (t < EPB) {
            float p = 0.f;
            #pragma unroll
            for (int ww = 0; ww < 8; ++ww) p += sPart[ww][t];
            sSg[e0 + t] = tanhf(p + cb0);
        }

        // msgL -> msgb (coalesced 16B stores)
        #pragma unroll
        for (int i = 0; i < 2; ++i) {
            int idx = i * 512 + t;          // 0..1023
            int e   = idx >> 4;
            int c   = idx & 15;
            *(s16x8*)&msgb[(size_t)(e0 + e) * FF + c * 8] =
                *(const s16x8*)&msgL[e * H1S + c * 8];
        }
        // no barrier needed here: next-iter writes (xa/dist2S) only touch state
        // whose last readers are all pre-(C); msgL's readers are this thread's
        // own copies above, and msgL is next written only after next-iter (B).
    }
}

// ==================== PASS B: CSR gather + MFMA node MLP + LN + pos =======
constexpr int NPB  = 16;
constexpr int ABS  = 136;   // bf16 LDS row stride (272 B = 17 quads, odd)

__global__ __launch_bounds__(128) void nodeB_kernel(
    const float* __restrict__ x, const float* __restrict__ pos,
    const unsigned short* __restrict__ msgb, const float* __restrict__ sSg,
    const int* __restrict__ sCol, const int* __restrict__ rowStart,
    const unsigned short* __restrict__ nw1T, const float* __restrict__ nb1,
    const unsigned short* __restrict__ nw2T, const float* __restrict__ nb2,
    const float* __restrict__ gamma, const float* __restrict__ beta,
    float* __restrict__ xout, float* __restrict__ posout)
{
    __shared__ __align__(16) unsigned short aB [NPB * ABS];   // agg tile, bf16
    __shared__ __align__(16) unsigned short h1B[NPB * ABS];
    __shared__ float sRedS[2][NPB];
    __shared__ float sRedQ[2][NPB];

    const int t   = threadIdx.x;
    const int w   = t >> 6;          // 0..1
    const int l   = t & 63;
    const int l15 = l & 15;
    const int q8  = l >> 4;

    const int n0 = blockIdx.x * NPB;

    // CSR gather (col t per thread, proven): agg -> bf16 LDS tile
    for (int e = 0; e < NPB; ++e) {
        int nn = n0 + e;
        int p0 = rowStart[nn];
        int p1 = (nn == NN - 1) ? EE : rowStart[nn + 1];
        float s0 = 0.f, s1 = 0.f, s2 = 0.f, s3 = 0.f;
        int p = p0;
        for (; p + 4 <= p1; p += 4) {
            s0 += bf2f(msgb[(size_t)(p    ) * FF + t]);
            s1 += bf2f(msgb[(size_t)(p + 1) * FF + t]);
            s2 += bf2f(msgb[(size_t)(p + 2) * FF + t]);
            s3 += bf2f(msgb[(size_t)(p + 3) * FF + t]);
        }
        for (; p < p1; ++p) s0 += bf2f(msgb[(size_t)p * FF + t]);
        aB[e * ABS + t] = f2bf((s0 + s1) + (s2 + s3));
    }

    // pos update (independent of MLP)
    if (t < NPB * 3) {
        int e = t / 3, d = t % 3;
        int nn = n0 + e;
        int p0 = rowStart[nn];
        int p1 = (nn == NN - 1) ? EE : rowStart[nn + 1];
        float pn = pos[nn * 3 + d];
        float sum = 0.f;
        for (int p = p0; p < p1; ++p) {
            int c = sCol[p];
            sum += sSg[p] * (pn - pos[c * 3 + d]);
        }
        posout[nn * 3 + d] = pn + sum;
    }
    __syncthreads();

    // wave w covers cols ncol[tt] = w*64 + tt*16 + l15
    int ncol[4];
    #pragma unroll
    for (int tt = 0; tt < 4; ++tt) ncol[tt] = w * 64 + tt * 16 + l15;

    // GEMM1 (16 nodes x 128 cols, K=128): A rows m=l15
    f32x4 acc[4] = {};
    {
        const unsigned short* ar = aB + l15 * ABS + q8 * 8;
        #pragma unroll
        for (int ko = 0; ko < 4; ++ko) {
            s16x8 a = *(const s16x8*)(ar + ko * 32);
            #pragma unroll
            for (int tt = 0; tt < 4; ++tt) {
                s16x8 b = *(const s16x8*)(nw1T + (size_t)ncol[tt] * 128 + ko * 32 + q8 * 8);
                acc[tt] = __builtin_amdgcn_mfma_f32_16x16x32_bf16(a, b, acc[tt], 0, 0, 0);
            }
        }
    }
    #pragma unroll
    for (int tt = 0; tt < 4; ++tt) {
        float bb = nb1[ncol[tt]];
        #pragma unroll
        for (int r = 0; r < 4; ++r) {
            int e = q8 * 4 + r;
            h1B[e * ABS + ncol[tt]] = f2bf(silu_f(acc[tt][r] + bb));
        }
    }
    __syncthreads();

    // GEMM2 (K=128)
    f32x4 acc2[4] = {};
    {
        const unsigned short* hr = h1B + l15 * ABS + q8 * 8;
        #pragma unroll
        for (int ko = 0; ko < 4; ++ko) {
            s16x8 a = *(const s16x8*)(hr + ko * 32);
            #pragma unroll
            for (int tt = 0; tt < 4; ++tt) {
                s16x8 b = *(const s16x8*)(nw2T + (size_t)ncol[tt] * 128 + ko * 32 + q8 * 8);
                acc2[tt] = __builtin_amdgcn_mfma_f32_16x16x32_bf16(a, b, acc2[tt], 0, 0, 0);
            }
        }
    }

    // residual + LN.  Lane holds rows e=q8*4+r, cols ncol[tt].
    float pre[4][4];
    #pragma unroll
    for (int tt = 0; tt < 4; ++tt) {
        float bb = nb2[ncol[tt]];
        #pragma unroll
        for (int r = 0; r < 4; ++r) {
            int e = q8 * 4 + r;
            pre[tt][r] = x[(size_t)(n0 + e) * FF + ncol[tt]] + acc2[tt][r] + bb;
        }
    }
    #pragma unroll
    for (int r = 0; r < 4; ++r) {
        float s = 0.f, sq = 0.f;
        #pragma unroll
        for (int tt = 0; tt < 4; ++tt) {
            s  += pre[tt][r];
            sq += pre[tt][r] * pre[tt][r];
        }
        s  += __shfl_xor(s, 1);  sq += __shfl_xor(sq, 1);
        s  += __shfl_xor(s, 2);  sq += __shfl_xor(sq, 2);
        s  += __shfl_xor(s, 4);  sq += __shfl_xor(sq, 4);
        s  += __shfl_xor(s, 8);  sq += __shfl_xor(sq, 8);
        if (l15 == 0) {
            int e = q8 * 4 + r;
            sRedS[w][e] = s;
            sRedQ[w][e] = sq;
        }
    }
    __syncthreads();

    #pragma unroll
    for (int tt = 0; tt < 4; ++tt) {
        float g = gamma[ncol[tt]], bb = beta[ncol[tt]];
        #pragma unroll
        for (int r = 0; r < 4; ++r) {
            int e = q8 * 4 + r;
            float mean = (sRedS[0][e] + sRedS[1][e]) * (1.f / FF);
            float m2   = (sRedQ[0][e] + sRedQ[1][e]) * (1.f / FF);
            float var  = m2 - mean * mean;
            float xo   = g * (pre[tt][r] - mean) * rsqrtf(var + LN_EPS) + bb;
            xout[(size_t)(n0 + e) * FF + ncol[tt]] = xo;
        }
    }
}

// -------------------- launcher --------------------
extern "C" void kernel_launch(void* const* d_in, const int* in_sizes, int n_in,
                              void* d_out, int out_size, void* d_ws, size_t ws_size,
                              hipStream_t stream) {
    const float* x    = (const float*)d_in[0];
    const float* pos  = (const float*)d_in[1];
    const int*   ei   = (const int*)  d_in[2];
    const float* ew1  = (const float*)d_in[3];
    const float* eb1  = (const float*)d_in[4];
    const float* ew2  = (const float*)d_in[5];
    const float* eb2  = (const float*)d_in[6];
    const float* nw1  = (const float*)d_in[7];
    const float* nb1  = (const float*)d_in[8];
    const float* nw2  = (const float*)d_in[9];
    const float* nb2  = (const float*)d_in[10];
    const float* cw   = (const float*)d_in[11];
    const float* cb   = (const float*)d_in[12];
    const float* gam  = (const float*)d_in[13];
    const float* bet  = (const float*)d_in[14];

    float* out    = (float*)d_out;
    float* xout   = out;
    float* posout = out + (size_t)NN * FF;

    auto align256 = [](size_t v) { return (v + 255) & ~(size_t)255; };
    char* ws = (char*)d_ws;

    size_t CNT_B   = align256((size_t)NN * 4);
    size_t OFFS_B  = align256((size_t)NN * 4);
    size_t RST_B   = align256((size_t)NN * 4);
    size_t CHNK_B  = align256((size_t)NC * 4 * 2);
    size_t SROW_B  = align256((size_t)EE * 4);
    size_t XB_B    = align256((size_t)NN * FF * 2);
    size_t EW1T_B  = align256((size_t)128 * 256 * 2);
    size_t WT_B    = align256((size_t)128 * 128 * 2);
    size_t MSGB_B  = align256((size_t)EE * FF * 2);   // 204.8 MB
    // sSg after msgb

    size_t o = 0;
    int* cnt       = (int*)(ws + o);  o += CNT_B;    // zeroed
    int* offs      = (int*)(ws + o);  o += OFFS_B;
    int* rowStart  = (int*)(ws + o);  o += RST_B;
    int* chunkSum  = (int*)(ws + o);
    int* chunkOff  = chunkSum + NC;   o += CHNK_B;
    int* sRow      = (int*)(ws + o);  o += SROW_B;
    int* sCol      = (int*)(ws + o);  o += SROW_B;
    unsigned short* xb   = (unsigned short*)(ws + o);  o += XB_B;
    unsigned short* ew1T = (unsigned short*)(ws + o);  o += EW1T_B;
    unsigned short* ew2T = (unsigned short*)(ws + o);  o += WT_B;
    unsigned short* nw1T = (unsigned short*)(ws + o);  o += WT_B;
    unsigned short* nw2T = (unsigned short*)(ws + o);  o += WT_B;
    unsigned short* msgb = (unsigned short*)(ws + o);  o += MSGB_B;
    float*          sSg  = (float*)(ws + o);

    hipMemsetAsync(cnt, 0, CNT_B, stream);

    convert_x_kernel<<<(NN * FF / 8) / 256, 256, 0, stream>>>(x, xb);
    transpose_w_kernel<<<(32768 + 3 * 16384) / 256, 256, 0, stream>>>(
        ew1, ew2, nw1, nw2, ew1T, ew2T, nw1T, nw2T);

    hist_kernel<<<(EE + 255) / 256, 256, 0, stream>>>(ei, cnt);
    chunk_sum_kernel<<<NC, 256, 0, stream>>>(cnt, chunkSum);
    scan_chunks_kernel<<<1, 256, 0, stream>>>(chunkSum, chunkOff);
    scan_kernel<<<NC, 256, 0, stream>>>(cnt, chunkOff, offs, rowStart);
    scatter_idx_kernel<<<(EE + 255) / 256, 256, 0, stream>>>(ei, offs, sRow, sCol);

    edgeA_kernel<<<2048, 512, 0, stream>>>(
        xb, pos, sRow, sCol, ew1T, ew1, eb1, ew2T, eb2, cw, cb, msgb, sSg);

    nodeB_kernel<<<NN / NPB, 128, 0, stream>>>(
        x, pos, msgb, sSg, sCol, rowStart,
        nw1T, nb1, nw2T, nb2, gam, bet, xout, posout);
}

// Round 8
// 516.985 us; speedup vs baseline: 1.4973x; 1.0206x over previous
//
#include <hip/hip_runtime.h>
#include <math.h>

#define NN 50000
#define EE 800000
#define FF 128

constexpr float LN_EPS = 1e-5f;
constexpr int NC = (NN + 255) / 256;   // 196 scan chunks

typedef float  f32x4  __attribute__((ext_vector_type(4)));
typedef short  s16x8  __attribute__((ext_vector_type(8)));

__device__ __forceinline__ float silu_f(float v) {
    return v / (1.f + __expf(-v));
}

__device__ __forceinline__ unsigned short f2bf(float f) {
    union { float f; unsigned u; } cv; cv.f = f;
    unsigned u = cv.u;
    u += 0x7fffu + ((u >> 16) & 1u);   // round-to-nearest-even
    return (unsigned short)(u >> 16);
}

__device__ __forceinline__ float bf2f(unsigned short u) {
    union { unsigned u; float f; } cv; cv.u = ((unsigned)u) << 16;
    return cv.f;
}

// -------------------- prep: x -> bf16 --------------------
__global__ __launch_bounds__(256) void convert_x_kernel(
    const float* __restrict__ x, unsigned short* __restrict__ xb)
{
    int i = (blockIdx.x * 256 + threadIdx.x) * 8;
    float4 a = *(const float4*)&x[i];
    float4 b = *(const float4*)&x[i + 4];
    s16x8 o;
    o[0] = (short)f2bf(a.x); o[1] = (short)f2bf(a.y);
    o[2] = (short)f2bf(a.z); o[3] = (short)f2bf(a.w);
    o[4] = (short)f2bf(b.x); o[5] = (short)f2bf(b.y);
    o[6] = (short)f2bf(b.z); o[7] = (short)f2bf(b.w);
    *(s16x8*)&xb[i] = o;
}

// -------------------- prep: transpose all weights -> bf16 --------------------
__global__ __launch_bounds__(256) void transpose_w_kernel(
    const float* __restrict__ ew1, const float* __restrict__ ew2,
    const float* __restrict__ nw1, const float* __restrict__ nw2,
    unsigned short* __restrict__ ew1T, unsigned short* __restrict__ ew2T,
    unsigned short* __restrict__ nw1T, unsigned short* __restrict__ nw2T)
{
    int o = blockIdx.x * 256 + threadIdx.x;
    if (o < 32768) {
        int n = o >> 8, k = o & 255;
        ew1T[o] = f2bf(ew1[k * FF + n]);
    } else if (o < 49152) {
        int o2 = o - 32768; int n = o2 >> 7, k = o2 & 127;
        ew2T[o2] = f2bf(ew2[k * FF + n]);
    } else if (o < 65536) {
        int o2 = o - 49152; int n = o2 >> 7, k = o2 & 127;
        nw1T[o2] = f2bf(nw1[k * FF + n]);
    } else {
        int o2 = o - 65536; int n = o2 >> 7, k = o2 & 127;
        nw2T[o2] = f2bf(nw2[k * FF + n]);
    }
}

// -------------------- counting sort by row --------------------
__global__ __launch_bounds__(256) void hist_kernel(
    const int* __restrict__ ei, int* __restrict__ cnt)
{
    int e = blockIdx.x * 256 + threadIdx.x;
    if (e < EE) atomicAdd(&cnt[ei[e]], 1);
}

__global__ __launch_bounds__(256) void chunk_sum_kernel(
    const int* __restrict__ cnt, int* __restrict__ chunkSum)
{
    __shared__ int s[256];
    int t = threadIdx.x;
    int idx = blockIdx.x * 256 + t;
    s[t] = (idx < NN) ? cnt[idx] : 0;
    __syncthreads();
    for (int off = 128; off > 0; off >>= 1) {
        if (t < off) s[t] += s[t + off];
        __syncthreads();
    }
    if (t == 0) chunkSum[blockIdx.x] = s[0];
}

__global__ __launch_bounds__(256) void scan_chunks_kernel(
    const int* __restrict__ chunkSum, int* __restrict__ chunkOff)
{
    __shared__ int s[256];
    int t = threadIdx.x;
    int v = (t < NC) ? chunkSum[t] : 0;
    s[t] = v;
    __syncthreads();
    for (int off = 1; off < 256; off <<= 1) {
        int u = (t >= off) ? s[t - off] : 0;
        __syncthreads();
        s[t] += u;
        __syncthreads();
    }
    if (t < NC) chunkOff[t] = s[t] - v;
}

__global__ __launch_bounds__(256) void scan_kernel(
    const int* __restrict__ cnt, const int* __restrict__ chunkOff,
    int* __restrict__ offs, int* __restrict__ rowStart)
{
    __shared__ int s[256];
    int t = threadIdx.x;
    int idx = blockIdx.x * 256 + t;
    int v = (idx < NN) ? cnt[idx] : 0;
    s[t] = v;
    __syncthreads();
    for (int off = 1; off < 256; off <<= 1) {
        int u = (t >= off) ? s[t - off] : 0;
        __syncthreads();
        s[t] += u;
        __syncthreads();
    }
    if (idx < NN) {
        int st = chunkOff[blockIdx.x] + s[t] - v;
        offs[idx] = st;
        rowStart[idx] = st;
    }
}

__global__ __launch_bounds__(256) void scatter_idx_kernel(
    const int* __restrict__ ei, int* __restrict__ offs,
    int* __restrict__ sRow, int* __restrict__ sCol)
{
    int e = blockIdx.x * 256 + threadIdx.x;
    if (e < EE) {
        int r = ei[e], c = ei[EE + e];
        int p = atomicAdd(&offs[r], 1);
        sRow[p] = r;
        sCol[p] = c;
    }
}

// ==================== PASS A: edge MLP -> msgb, sSg (pipelined) ===========
constexpr int EPB   = 64;
constexpr int NTILE = EE / EPB;    // 12500
constexpr int XAS   = 264;         // xa stride: 528 B row (33 quads, odd)
constexpr int H1S   = 136;         // h1/msgL stride: 272 B row (17 quads, odd)

__global__ __launch_bounds__(512, 4) void edgeA_kernel(
    const unsigned short* __restrict__ xb, const float* __restrict__ pos,
    const int* __restrict__ sRow, const int* __restrict__ sCol,
    const unsigned short* __restrict__ ew1T, const float* __restrict__ ew1,
    const float* __restrict__ eb1,
    const unsigned short* __restrict__ ew2T, const float* __restrict__ eb2,
    const float* __restrict__ cw,  const float* __restrict__ cb,
    unsigned short* __restrict__ msgb, float* __restrict__ sSg)
{
    __shared__ float dist2S[EPB];
    __shared__ float sPart[8][EPB];
    __shared__ __align__(16) unsigned short xa  [EPB * XAS];
    __shared__ __align__(16) unsigned short h1  [EPB * H1S];
    __shared__ __align__(16) unsigned short msgL[EPB * H1S];

    const int t   = threadIdx.x;
    const int w   = t >> 6;
    const int l   = t & 63;
    const int l15 = l & 15;
    const int q8  = l >> 4;
    const int n   = w * 16 + l15;

    s16x8 B1[8], B2[4];
    #pragma unroll
    for (int ko = 0; ko < 8; ++ko)
        B1[ko] = *(const s16x8*)(ew1T + (size_t)n * 256 + ko * 32 + q8 * 8);
    #pragma unroll
    for (int ko = 0; ko < 4; ++ko)
        B2[ko] = *(const s16x8*)(ew2T + (size_t)n * 128 + ko * 32 + q8 * 8);
    const float w256 = ew1[256 * FF + n];
    const float b1   = eb1[n];
    const float b2   = eb2[n];
    const float cwc  = cw[n];
    const float cb0  = cb[0];

    const int q   = t & 31;
    const int eB  = t >> 5;
    const int ksel = (q & 15) * 8;
    const int* idxBase = (q < 16) ? sRow : sCol;

    int   nidx[4];
    s16x8 ag[4];
    {
        int e0 = blockIdx.x * EPB;
        #pragma unroll
        for (int i = 0; i < 4; ++i) nidx[i] = idxBase[e0 + eB + 16 * i];
        #pragma unroll
        for (int i = 0; i < 4; ++i) ag[i] = *(const s16x8*)(xb + (size_t)nidx[i] * FF + ksel);
    }

    for (int tile = blockIdx.x; tile < NTILE; tile += gridDim.x) {
        const int e0 = tile * EPB;

        #pragma unroll
        for (int i = 0; i < 4; ++i)
            *(s16x8*)(xa + (eB + 16 * i) * XAS + q * 8) = ag[i];
        if (t < EPB) {
            int r = sRow[e0 + t];
            int c = sCol[e0 + t];
            float dx = pos[r*3+0] - pos[c*3+0];
            float dy = pos[r*3+1] - pos[c*3+1];
            float dz = pos[r*3+2] - pos[c*3+2];
            dist2S[t] = dx*dx + dy*dy + dz*dz;
        }
        __syncthreads();   // (A)

        {
            int tn  = tile + gridDim.x;
            int e0n = (tn < NTILE) ? tn * EPB : 0;
            #pragma unroll
            for (int i = 0; i < 4; ++i) nidx[i] = idxBase[e0n + eB + 16 * i];
            #pragma unroll
            for (int i = 0; i < 4; ++i) ag[i] = *(const s16x8*)(xb + (size_t)nidx[i] * FF + ksel);
        }

        f32x4 acc[4] = {};
        #pragma unroll
        for (int mt = 0; mt < 4; ++mt) {
            const unsigned short* ar = xa + (mt * 16 + l15) * XAS + q8 * 8;
            #pragma unroll
            for (int ko = 0; ko < 8; ++ko) {
                s16x8 a = *(const s16x8*)(ar + ko * 32);
                acc[mt] = __builtin_amdgcn_mfma_f32_16x16x32_bf16(a, B1[ko], acc[mt], 0, 0, 0);
            }
        }

        #pragma unroll
        for (int mt = 0; mt < 4; ++mt) {
            #pragma unroll
            for (int r = 0; r < 4; ++r) {
                int e = mt * 16 + q8 * 4 + r;
                float v = acc[mt][r] + dist2S[e] * w256 + b1;
                h1[e * H1S + n] = f2bf(silu_f(v));
            }
        }
        __syncthreads();   // (B)

        f32x4 acc2[4] = {};
        #pragma unroll
        for (int mt = 0; mt < 4; ++mt) {
            const unsigned short* hr = h1 + (mt * 16 + l15) * H1S + q8 * 8;
            #pragma unroll
            for (int ko = 0; ko < 4; ++ko) {
                s16x8 a = *(const s16x8*)(hr + ko * 32);
                acc2[mt] = __builtin_amdgcn_mfma_f32_16x16x32_bf16(a, B2[ko], acc2[mt], 0, 0, 0);
            }
        }

        #pragma unroll
        for (int mt = 0; mt < 4; ++mt) {
            #pragma unroll
            for (int r = 0; r < 4; ++r) {
                float m = acc2[mt][r] + b2;
                float p = m * cwc;
                p += __shfl_xor(p, 1);
                p += __shfl_xor(p, 2);
                p += __shfl_xor(p, 4);
                p += __shfl_xor(p, 8);
                int e = mt * 16 + q8 * 4 + r;
                if (l15 == 0) sPart[w][e] = p;
                msgL[e * H1S + n] = f2bf(m);
            }
        }
        __syncthreads();   // (C)

        if (t < EPB) {
            float p = 0.f;
            #pragma unroll
            for (int ww = 0; ww < 8; ++ww) p += sPart[ww][t];
            sSg[e0 + t] = tanhf(p + cb0);
        }

        #pragma unroll
        for (int i = 0; i < 2; ++i) {
            int idx = i * 512 + t;
            int e   = idx >> 4;
            int c   = idx & 15;
            *(s16x8*)&msgb[(size_t)(e0 + e) * FF + c * 8] =
                *(const s16x8*)&msgL[e * H1S + c * 8];
        }
    }
}

// ==================== PASS B: wave-gather + MFMA node MLP + LN + pos ======
constexpr int NPB = 16;
constexpr int ABS = 136;   // bf16 LDS row stride (272 B, odd quads)

__global__ __launch_bounds__(512) void nodeB_kernel(
    const float* __restrict__ x, const float* __restrict__ pos,
    const unsigned short* __restrict__ msgb, const float* __restrict__ sSg,
    const int* __restrict__ sCol, const int* __restrict__ rowStart,
    const unsigned short* __restrict__ nw1T, const float* __restrict__ nb1,
    const unsigned short* __restrict__ nw2T, const float* __restrict__ nb2,
    const float* __restrict__ gamma, const float* __restrict__ beta,
    float* __restrict__ xout, float* __restrict__ posout)
{
    __shared__ __align__(16) unsigned short aB [NPB * ABS];
    __shared__ __align__(16) unsigned short h1B[NPB * ABS];
    __shared__ float sRedS[8][NPB];
    __shared__ float sRedQ[8][NPB];

    const int t   = threadIdx.x;
    const int w   = t >> 6;          // 0..7
    const int l   = t & 63;
    const int l15 = l & 15;
    const int q8  = l >> 4;          // 0..3
    const int n0  = blockIdx.x * NPB;
    const int n   = w * 16 + l15;    // this wave's output column

    // ---- gather: wave w sums msgb rows for nodes 2w, 2w+1 ----
    // lane group q8 takes row p+q8; lane l15 takes 16 B of columns.
    // whole wave reads 1 KB contiguous per iteration.
    #pragma unroll
    for (int s = 0; s < 2; ++s) {
        int e  = 2 * w + s;
        int nn = n0 + e;
        int p0 = rowStart[nn];
        int p1 = (nn == NN - 1) ? EE : rowStart[nn + 1];
        float a0=0.f,a1=0.f,a2=0.f,a3=0.f,a4=0.f,a5=0.f,a6=0.f,a7=0.f;
        for (int p = p0 + q8; p < p1; p += 4) {
            s16x8 v = *(const s16x8*)(msgb + (size_t)p * FF + l15 * 8);
            a0 += bf2f((unsigned short)v[0]);
            a1 += bf2f((unsigned short)v[1]);
            a2 += bf2f((unsigned short)v[2]);
            a3 += bf2f((unsigned short)v[3]);
            a4 += bf2f((unsigned short)v[4]);
            a5 += bf2f((unsigned short)v[5]);
            a6 += bf2f((unsigned short)v[6]);
            a7 += bf2f((unsigned short)v[7]);
        }
        a0 += __shfl_xor(a0,16); a1 += __shfl_xor(a1,16);
        a2 += __shfl_xor(a2,16); a3 += __shfl_xor(a3,16);
        a4 += __shfl_xor(a4,16); a5 += __shfl_xor(a5,16);
        a6 += __shfl_xor(a6,16); a7 += __shfl_xor(a7,16);
        a0 += __shfl_xor(a0,32); a1 += __shfl_xor(a1,32);
        a2 += __shfl_xor(a2,32); a3 += __shfl_xor(a3,32);
        a4 += __shfl_xor(a4,32); a5 += __shfl_xor(a5,32);
        a6 += __shfl_xor(a6,32); a7 += __shfl_xor(a7,32);
        if (q8 == 0) {
            s16x8 o;
            o[0]=(short)f2bf(a0); o[1]=(short)f2bf(a1);
            o[2]=(short)f2bf(a2); o[3]=(short)f2bf(a3);
            o[4]=(short)f2bf(a4); o[5]=(short)f2bf(a5);
            o[6]=(short)f2bf(a6); o[7]=(short)f2bf(a7);
            *(s16x8*)(aB + e * ABS + l15 * 8) = o;
        }
    }

    // ---- pos update (48 threads, independent) ----
    if (t < NPB * 3) {
        int e = t / 3, d = t % 3;
        int nn = n0 + e;
        int p0 = rowStart[nn];
        int p1 = (nn == NN - 1) ? EE : rowStart[nn + 1];
        float pn = pos[nn * 3 + d];
        float sum = 0.f;
        for (int p = p0; p < p1; ++p) {
            int c = sCol[p];
            sum += sSg[p] * (pn - pos[c * 3 + d]);
        }
        posout[nn * 3 + d] = pn + sum;
    }
    __syncthreads();

    // ---- GEMM1 (16 nodes x 128 cols, K=128): wave w -> 16 cols ----
    f32x4 acc = {};
    {
        const unsigned short* ar = aB + l15 * ABS + q8 * 8;
        #pragma unroll
        for (int ko = 0; ko < 4; ++ko) {
            s16x8 a = *(const s16x8*)(ar + ko * 32);
            s16x8 b = *(const s16x8*)(nw1T + (size_t)n * 128 + ko * 32 + q8 * 8);
            acc = __builtin_amdgcn_mfma_f32_16x16x32_bf16(a, b, acc, 0, 0, 0);
        }
    }
    {
        float bb = nb1[n];
        #pragma unroll
        for (int r = 0; r < 4; ++r) {
            int e = q8 * 4 + r;
            h1B[e * ABS + n] = f2bf(silu_f(acc[r] + bb));
        }
    }
    __syncthreads();

    // ---- GEMM2 (K=128) ----
    f32x4 acc2 = {};
    {
        const unsigned short* hr = h1B + l15 * ABS + q8 * 8;
        #pragma unroll
        for (int ko = 0; ko < 4; ++ko) {
            s16x8 a = *(const s16x8*)(hr + ko * 32);
            s16x8 b = *(const s16x8*)(nw2T + (size_t)n * 128 + ko * 32 + q8 * 8);
            acc2 = __builtin_amdgcn_mfma_f32_16x16x32_bf16(a, b, acc2, 0, 0, 0);
        }
    }

    // ---- residual + LN ----
    float pre[4];
    {
        float bb = nb2[n];
        #pragma unroll
        for (int r = 0; r < 4; ++r) {
            int e = q8 * 4 + r;
            pre[r] = x[(size_t)(n0 + e) * FF + n] + acc2[r] + bb;
        }
    }
    #pragma unroll
    for (int r = 0; r < 4; ++r) {
        float s = pre[r], sq = pre[r] * pre[r];
        s += __shfl_xor(s, 1);  sq += __shfl_xor(sq, 1);
        s += __shfl_xor(s, 2);  sq += __shfl_xor(sq, 2);
        s += __shfl_xor(s, 4);  sq += __shfl_xor(sq, 4);
        s += __shfl_xor(s, 8);  sq += __shfl_xor(sq, 8);
        if (l15 == 0) {
            int e = q8 * 4 + r;
            sRedS[w][e] = s;
            sRedQ[w][e] = sq;
        }
    }
    __syncthreads();

    {
        float g = gamma[n], bt = beta[n];
        #pragma unroll
        for (int r = 0; r < 4; ++r) {
            int e = q8 * 4 + r;
            float S = 0.f, Q = 0.f;
            #pragma unroll
            for (int ww = 0; ww < 8; ++ww) { S += sRedS[ww][e]; Q += sRedQ[ww][e]; }
            float mean = S * (1.f / FF);
            float var  = Q * (1.f / FF) - mean * mean;
            xout[(size_t)(n0 + e) * FF + n] =
                g * (pre[r] - mean) * rsqrtf(var + LN_EPS) + bt;
        }
    }
}

// -------------------- launcher --------------------
extern "C" void kernel_launch(void* const* d_in, const int* in_sizes, int n_in,
                              void* d_out, int out_size, void* d_ws, size_t ws_size,
                              hipStream_t stream) {
    const float* x    = (const float*)d_in[0];
    const float* pos  = (const float*)d_in[1];
    const int*   ei   = (const int*)  d_in[2];
    const float* ew1  = (const float*)d_in[3];
    const float* eb1  = (const float*)d_in[4];
    const float* ew2  = (const float*)d_in[5];
    const float* eb2  = (const float*)d_in[6];
    const float* nw1  = (const float*)d_in[7];
    const float* nb1  = (const float*)d_in[8];
    const float* nw2  = (const float*)d_in[9];
    const float* nb2  = (const float*)d_in[10];
    const float* cw   = (const float*)d_in[11];
    const float* cb   = (const float*)d_in[12];
    const float* gam  = (const float*)d_in[13];
    const float* bet  = (const float*)d_in[14];

    float* out    = (float*)d_out;
    float* xout   = out;
    float* posout = out + (size_t)NN * FF;

    auto align256 = [](size_t v) { return (v + 255) & ~(size_t)255; };
    char* ws = (char*)d_ws;

    size_t CNT_B   = align256((size_t)NN * 4);
    size_t OFFS_B  = align256((size_t)NN * 4);
    size_t RST_B   = align256((size_t)NN * 4);
    size_t CHNK_B  = align256((size_t)NC * 4 * 2);
    size_t SROW_B  = align256((size_t)EE * 4);
    size_t XB_B    = align256((size_t)NN * FF * 2);
    size_t EW1T_B  = align256((size_t)128 * 256 * 2);
    size_t WT_B    = align256((size_t)128 * 128 * 2);
    size_t MSGB_B  = align256((size_t)EE * FF * 2);   // 204.8 MB

    size_t o = 0;
    int* cnt       = (int*)(ws + o);  o += CNT_B;    // zeroed
    int* offs      = (int*)(ws + o);  o += OFFS_B;
    int* rowStart  = (int*)(ws + o);  o += RST_B;
    int* chunkSum  = (int*)(ws + o);
    int* chunkOff  = chunkSum + NC;   o += CHNK_B;
    int* sRow      = (int*)(ws + o);  o += SROW_B;
    int* sCol      = (int*)(ws + o);  o += SROW_B;
    unsigned short* xb   = (unsigned short*)(ws + o);  o += XB_B;
    unsigned short* ew1T = (unsigned short*)(ws + o);  o += EW1T_B;
    unsigned short* ew2T = (unsigned short*)(ws + o);  o += WT_B;
    unsigned short* nw1T = (unsigned short*)(ws + o);  o += WT_B;
    unsigned short* nw2T = (unsigned short*)(ws + o);  o += WT_B;
    unsigned short* msgb = (unsigned short*)(ws + o);  o += MSGB_B;
    float*          sSg  = (float*)(ws + o);

    hipMemsetAsync(cnt, 0, CNT_B, stream);

    convert_x_kernel<<<(NN * FF / 8) / 256, 256, 0, stream>>>(x, xb);
    transpose_w_kernel<<<(32768 + 3 * 16384) / 256, 256, 0, stream>>>(
        ew1, ew2, nw1, nw2, ew1T, ew2T, nw1T, nw2T);

    hist_kernel<<<(EE + 255) / 256, 256, 0, stream>>>(ei, cnt);
    chunk_sum_kernel<<<NC, 256, 0, stream>>>(cnt, chunkSum);
    scan_chunks_kernel<<<1, 256, 0, stream>>>(chunkSum, chunkOff);
    scan_kernel<<<NC, 256, 0, stream>>>(cnt, chunkOff, offs, rowStart);
    scatter_idx_kernel<<<(EE + 255) / 256, 256, 0, stream>>>(ei, offs, sRow, sCol);

    edgeA_kernel<<<2048, 512, 0, stream>>>(
        xb, pos, sRow, sCol, ew1T, ew1, eb1, ew2T, eb2, cw, cb, msgb, sSg);

    nodeB_kernel<<<NN / NPB, 512, 0, stream>>>(
        x, pos, msgb, sSg, sCol, rowStart,
        nw1T, nb1, nw2T, nb2, gam, bet, xout, posout);
}